// Round 1
// baseline (506.997 us; speedup 1.0000x reference)
//
#include <hip/hip_runtime.h>
#include <stdint.h>

typedef unsigned short u16;
typedef __bf16 bf16x8 __attribute__((ext_vector_type(8)));
typedef float f32x4 __attribute__((ext_vector_type(4)));
typedef short s16x8 __attribute__((ext_vector_type(8)));
typedef short s16x4 __attribute__((ext_vector_type(4)));

__device__ __forceinline__ u16 f2bf(float f) {
  unsigned u = __float_as_uint(f);
  u += 0x7fff + ((u >> 16) & 1);   // RNE
  return (u16)(u >> 16);
}

__device__ __forceinline__ void gld16(const void* g, void* l) {
  __builtin_amdgcn_global_load_lds((const __attribute__((address_space(1))) void*)g,
                                   (__attribute__((address_space(3))) void*)l, 16, 0, 0);
}

// ---------------- casts ----------------
__global__ void cast_f32_bf16(const float* __restrict__ in, u16* __restrict__ out, int n) {
  int stride = gridDim.x * blockDim.x;
  for (int i = blockIdx.x * blockDim.x + threadIdx.x; i * 4 < n; i += stride) {
    f32x4 v = *(const f32x4*)(in + (size_t)i * 4);
    s16x4 o;
#pragma unroll
    for (int j = 0; j < 4; ++j) o[j] = (short)f2bf(v[j]);
    *(s16x4*)(out + (size_t)i * 4) = o;
  }
}

// W_O [hd][m] fp32 -> Wot [m][hd] bf16
__global__ void transpose_cast(const float* __restrict__ in, u16* __restrict__ out, int R, int C) {
  int idx = blockIdx.x * 256 + threadIdx.x;
  if (idx < R * C) {
    int r = idx / C, c = idx - r * C;
    out[(size_t)c * R + r] = f2bf(in[idx]);
  }
}

// ---------------- GEMM: C[M,N] = A[M,K] * B[N,K]^T (bf16 in, fp32 acc) ----------------
// 128x128 tile, BK=64, 4 waves (2x2), each wave 64x64 via 4x4 frags of 16x16x32.
// LDS XOR-swizzle (byte ^= (row&7)<<4) with pre-swizzled global source for global_load_lds.
template<int F32OUT>
__global__ __launch_bounds__(256, 2)
void gemm_bt(const u16* __restrict__ A, const u16* __restrict__ B,
             void* __restrict__ Cv, int M, int N, int K) {
  __shared__ __align__(16) u16 As[128 * 64];
  __shared__ __align__(16) u16 Bs[128 * 64];
  const int tid = threadIdx.x;
  const int lane = tid & 63;
  const int wave = tid >> 6;
  const int wr = wave >> 1, wc = wave & 1;
  const int row0 = blockIdx.y * 128, col0 = blockIdx.x * 128;
  const u16* Ab = A + (size_t)row0 * K;
  const u16* Bb = B + (size_t)col0 * K;
  f32x4 acc[4][4] = {};
  for (int kt = 0; kt < K; kt += 64) {
#pragma unroll
    for (int i = 0; i < 4; ++i) {
      int c = i * 256 + tid;         // 16B chunk id (phys, linear in LDS)
      int o = c << 4;                // phys byte
      int row = o >> 7;              // 128B per row
      int ol = o ^ ((row & 7) << 4); // logical byte (involution)
      int colel = (ol & 127) >> 1;
      int ldsoff = (i * 256 + wave * 64) << 4;  // wave-uniform base
      gld16(Ab + (size_t)row * K + kt + colel, (char*)As + ldsoff);
      gld16(Bb + (size_t)row * K + kt + colel, (char*)Bs + ldsoff);
    }
    __syncthreads();
#pragma unroll
    for (int ks = 0; ks < 2; ++ks) {
      const int kb = ks * 64 + ((lane >> 4) << 4);  // byte offset of this lane's 8 k-elems
      bf16x8 af[4], bfr[4];
#pragma unroll
      for (int m = 0; m < 4; ++m) {
        int r = wr * 64 + m * 16 + (lane & 15);
        int o = ((r << 7) + kb) ^ ((r & 7) << 4);
        af[m] = *(const bf16x8*)((const char*)As + o);
      }
#pragma unroll
      for (int n = 0; n < 4; ++n) {
        int r = wc * 64 + n * 16 + (lane & 15);
        int o = ((r << 7) + kb) ^ ((r & 7) << 4);
        bfr[n] = *(const bf16x8*)((const char*)Bs + o);
      }
#pragma unroll
      for (int m = 0; m < 4; ++m)
#pragma unroll
        for (int n = 0; n < 4; ++n)
          acc[m][n] = __builtin_amdgcn_mfma_f32_16x16x32_bf16(af[m], bfr[n], acc[m][n], 0, 0, 0);
    }
    __syncthreads();
  }
  // epilogue: C/D layout col=lane&15, row=(lane>>4)*4+reg
#pragma unroll
  for (int m = 0; m < 4; ++m) {
#pragma unroll
    for (int r = 0; r < 4; ++r) {
      int row = row0 + wr * 64 + m * 16 + ((lane >> 4) << 2) + r;
      int colb = col0 + wc * 64 + (lane & 15);
#pragma unroll
      for (int n = 0; n < 4; ++n) {
        float v = acc[m][n][r];
        if (F32OUT) ((float*)Cv)[(size_t)row * N + colb + n * 16] = v;
        else        ((u16*)Cv)[(size_t)row * N + colb + n * 16] = f2bf(v);
      }
    }
  }
}

// ---------------- flash attention (causal), Dh=64 ----------------
// grid (S/64, H, B); 4 waves, wave w owns q-rows [q0+16w, q0+16w+16)
__global__ __launch_bounds__(256, 2)
void attn_fwd(const u16* __restrict__ Qg, const u16* __restrict__ Kg,
              const u16* __restrict__ Vg, u16* __restrict__ Og,
              int S, int H) {
  __shared__ __align__(16) u16 Ks[64 * 64];      // [k][d], XOR-swizzled
  __shared__ __align__(16) u16 Vt[64 * 64];      // [d][k], XOR-swizzled
  __shared__ __align__(16) u16 Ps[4][16 * 64];   // per-wave P [q][k], XOR-swizzled
  const int tid = threadIdx.x, lane = tid & 63, wave = tid >> 6;
  const int qt = blockIdx.x, h = blockIdx.y, b = blockIdx.z;
  const int q0 = qt * 64;
  const int D = H * 64;
  const int l15 = lane & 15, lg = lane >> 4;

  const int qrow = q0 + wave * 16 + l15;
  const u16* qp = Qg + (size_t)(b * S + qrow) * D + h * 64 + (lg << 3);
  bf16x8 qf0 = *(const bf16x8*)qp;
  bf16x8 qf1 = *(const bf16x8*)(qp + 32);

  f32x4 accO[4] = {};
  float mrow[4], lrow[4];
#pragma unroll
  for (int r = 0; r < 4; ++r) { mrow[r] = -__builtin_inff(); lrow[r] = 0.f; }

  for (int kt = 0; kt <= qt; ++kt) {
    const int k0 = kt * 64;
    // stage K tile (64x64) swizzled via global_load_lds
#pragma unroll
    for (int i = 0; i < 2; ++i) {
      int c = i * 256 + tid;
      int o = c << 4;
      int row = o >> 7;
      int ol = o ^ ((row & 7) << 4);
      int colel = (ol & 127) >> 1;
      gld16(Kg + (size_t)(b * S + k0 + row) * D + h * 64 + colel,
            (char*)Ks + i * 4096 + wave * 1024);
    }
    // stage V transposed ([d][k]) through regs, swizzled on rows d
#pragma unroll
    for (int i = 0; i < 2; ++i) {
      int c = i * 256 + tid;
      int k = c >> 3, d0 = (c & 7) << 3;
      s16x8 v = *(const s16x8*)(Vg + (size_t)(b * S + k0 + k) * D + h * 64 + d0);
#pragma unroll
      for (int j = 0; j < 8; ++j) {
        int d = d0 + j;
        int ob = ((d << 7) + (k << 1)) ^ ((d & 7) << 4);
        *(short*)((char*)Vt + ob) = v[j];
      }
    }
    __syncthreads();

    // S = Q K^T (16 q-rows x 64 k), fp32
    f32x4 sf[4] = {};
#pragma unroll
    for (int dstep = 0; dstep < 2; ++dstep) {
      const int kb = dstep * 64 + (lg << 4);
      bf16x8 qa = dstep ? qf1 : qf0;
#pragma unroll
      for (int kf = 0; kf < 4; ++kf) {
        int r = kf * 16 + l15;
        int o = ((r << 7) + kb) ^ ((r & 7) << 4);
        bf16x8 kb8 = *(const bf16x8*)((const char*)Ks + o);
        sf[kf] = __builtin_amdgcn_mfma_f32_16x16x32_bf16(qa, kb8, sf[kf], 0, 0, 0);
      }
    }

    // scale + causal mask + online softmax (C-layout: row=(lg<<2)+r, col=kf*16+l15)
    float rmax[4];
#pragma unroll
    for (int r = 0; r < 4; ++r) rmax[r] = -__builtin_inff();
    const int qbase = q0 + wave * 16 + (lg << 2);
    const bool diag = (kt == qt);
#pragma unroll
    for (int kf = 0; kf < 4; ++kf) {
      int kcol = k0 + kf * 16 + l15;
#pragma unroll
      for (int r = 0; r < 4; ++r) {
        float s = sf[kf][r] * 0.125f;
        if (diag && kcol > qbase + r) s = -__builtin_inff();
        sf[kf][r] = s;
        rmax[r] = fmaxf(rmax[r], s);
      }
    }
#pragma unroll
    for (int off = 1; off < 16; off <<= 1)
#pragma unroll
      for (int r = 0; r < 4; ++r)
        rmax[r] = fmaxf(rmax[r], __shfl_xor(rmax[r], off, 64));
    float fr[4], psum[4];
#pragma unroll
    for (int r = 0; r < 4; ++r) {
      float mnew = fmaxf(mrow[r], rmax[r]);
      fr[r] = __expf(mrow[r] - mnew);   // 0 on first tile (mrow=-inf, mnew finite)
      mrow[r] = mnew;
      lrow[r] *= fr[r];
      psum[r] = 0.f;
    }
#pragma unroll
    for (int kf = 0; kf < 4; ++kf) {
#pragma unroll
      for (int r = 0; r < 4; ++r) {
        float p = __expf(sf[kf][r] - mrow[r]);
        psum[r] += p;
        int prow = (lg << 2) + r;
        int pcol = kf * 16 + l15;
        int ob = ((prow << 7) + (pcol << 1)) ^ ((prow & 7) << 4);
        *(u16*)((char*)&Ps[wave][0] + ob) = f2bf(p);
      }
    }
#pragma unroll
    for (int off = 1; off < 16; off <<= 1)
#pragma unroll
      for (int r = 0; r < 4; ++r)
        psum[r] += __shfl_xor(psum[r], off, 64);
#pragma unroll
    for (int r = 0; r < 4; ++r) lrow[r] += psum[r];
#pragma unroll
    for (int df = 0; df < 4; ++df)
#pragma unroll
      for (int r = 0; r < 4; ++r) accO[df][r] *= fr[r];

    // O += P V   (P per-wave in LDS; same-wave ds_write->ds_read, no barrier needed)
#pragma unroll
    for (int ks = 0; ks < 2; ++ks) {
      const int kb = ks * 64 + (lg << 4);
      int po = ((l15 << 7) + kb) ^ ((l15 & 7) << 4);
      bf16x8 pa = *(const bf16x8*)((const char*)&Ps[wave][0] + po);
#pragma unroll
      for (int df = 0; df < 4; ++df) {
        int vr = df * 16 + l15;
        int vo = ((vr << 7) + kb) ^ ((vr & 7) << 4);
        bf16x8 vb8 = *(const bf16x8*)((const char*)Vt + vo);
        accO[df] = __builtin_amdgcn_mfma_f32_16x16x32_bf16(pa, vb8, accO[df], 0, 0, 0);
      }
    }
    __syncthreads();  // protect Ks/Vt before next-tile staging
  }

  // write attn_out [b*S+q][h*64+d] bf16
#pragma unroll
  for (int df = 0; df < 4; ++df) {
#pragma unroll
    for (int r = 0; r < 4; ++r) {
      int row = q0 + wave * 16 + (lg << 2) + r;
      int col = h * 64 + df * 16 + l15;
      Og[(size_t)(b * S + row) * D + col] = f2bf(accO[df][r] / lrow[r]);
    }
  }
}

// ---------------- launch ----------------
extern "C" void kernel_launch(void* const* d_in, const int* in_sizes, int n_in,
                              void* d_out, int out_size, void* d_ws, size_t ws_size,
                              hipStream_t stream) {
  const float* residual = (const float*)d_in[0];
  const float* W_Q = (const float*)d_in[1];
  const float* W_K = (const float*)d_in[2];
  const float* W_V = (const float*)d_in[3];
  const float* W_O = (const float*)d_in[4];
  float* out = (float*)d_out;
  const int B = 4, S = 2048, D = 1024, H = 16;
  const int M = B * S;  // 8192

  char* ws = (char*)d_ws;
  size_t off = 0;
  auto alloc = [&](size_t elems) {
    u16* p = (u16*)(ws + off);
    off += ((elems * 2 + 255) & ~(size_t)255);
    return p;
  };
  u16* resb = alloc((size_t)M * D);
  u16* Wqb  = alloc((size_t)D * D);
  u16* Wkb  = alloc((size_t)D * D);
  u16* Wvb  = alloc((size_t)D * D);
  u16* Wot  = alloc((size_t)D * D);
  u16* Qw   = alloc((size_t)M * D);
  u16* Kw   = alloc((size_t)M * D);
  u16* Vw   = alloc((size_t)M * D);
  u16* AOw  = resb;  // residual-bf16 is dead after the QKV GEMMs — alias

  cast_f32_bf16<<<1024, 256, 0, stream>>>(residual, resb, M * D);
  cast_f32_bf16<<<256, 256, 0, stream>>>(W_Q, Wqb, D * D);
  cast_f32_bf16<<<256, 256, 0, stream>>>(W_K, Wkb, D * D);
  cast_f32_bf16<<<256, 256, 0, stream>>>(W_V, Wvb, D * D);
  transpose_cast<<<(D * D + 255) / 256, 256, 0, stream>>>(W_O, Wot, D, D);

  dim3 g(D / 128, M / 128);  // (8, 64)
  gemm_bt<0><<<g, 256, 0, stream>>>(resb, Wqb, Qw, M, D, D);
  gemm_bt<0><<<g, 256, 0, stream>>>(resb, Wkb, Kw, M, D, D);
  gemm_bt<0><<<g, 256, 0, stream>>>(resb, Wvb, Vw, M, D, D);

  attn_fwd<<<dim3(S / 64, H, B), 256, 0, stream>>>(Qw, Kw, Vw, AOw, S, H);

  gemm_bt<1><<<g, 256, 0, stream>>>(AOw, Wot, out, M, D, D);
}